// Round 8
// baseline (145.779 us; speedup 1.0000x reference)
//
#include <hip/hip_runtime.h>

// InfoNCE loss:
//   loss = (1/B) * sum_i [ log(sum_j exp(Q_i . D_j / T)) - Q_i . D_{i*dp} / T ]
// Logits bounded (|logit| < ~10) -> no max-subtraction; per-row sum-exp is
// commutative -> atomicAdd merge across column-blocks.
//
// R8 = R4 (best GEMM: 44.7us/1537TF, single-buffer 2-barrier K-loop; R6/R7
// proved bigger tiles and explicit dbuf both lose to occupancy) with:
//  - final_kernel FUSED via fence-free watcher block (grid 2048+1):
//    workers: epilogue atomics (device-scope) -> __syncthreads (compiler
//    drains vmcnt(0) per wave -> atomics globally performed) -> ONE relaxed
//    agent-scope counter add. NO threadfence/ACQ_REL anywhere in workers
//    (R5 showed per-block buffer_wbl2/inv = 2.5x GEMM regression).
//    pos[] written with relaxed agent-scope atomic stores (coherent, no
//    cache maintenance). Watcher spins on counter, reduces with relaxed
//    agent-scope loads, writes out[0]. Saves one dispatch boundary.
//  - XCD-aware swizzle: 1D grid, id&7 = XCD; each XCD owns an 8x32
//    (Q-tile x D-tile) rectangle -> ~5MB working set ~= its 4MB L2.
//
// Tiled layout (per matrix): for 128-row block R, 128-wide k-block k0b:
//   16KB image = 16 chunks x 1KB. Chunk c = rg*2 + kh (rg=0..7 16-row group,
//   kh=0..1 64-col half); slot l (16B) holds
//   X[R*128 + rg*16 + (l&15)][k0b*128 + kh*64 + (l>>4)*16 .. +16]   (fp8)
//
// ws layout (~12.1 MB):
//   [0)       Q8  B*K fp8     (4 MB)
//   [B*K)     D8  N*K fp8     (8 MB)
//   [+N*K)    rowsum B f32    (16 KB)  zeroed by cvt kernel
//   [+B*4)    pos    B f32    (16 KB)  written by gemm epilogue
//   [+B*4)    cnt    1 u32             zeroed by cvt kernel

#define TEMP_INV 50.0f
#define PRESCALE 16.0f
#define SCALE_BYTE 123   // e8m0: 2^(123-127) = 2^-4 per operand
#define KD 1024          // DIM (fixed by problem shape)

typedef int   i32x4 __attribute__((ext_vector_type(4)));
typedef int   i32x8 __attribute__((ext_vector_type(8)));
typedef float f32x4 __attribute__((ext_vector_type(4)));

// ---------------- fp32 -> fp8 e4m3 (x16), pre-tiled; zero rowsum+cnt ------
// One thread per 16B output slot (R4's verified cvt). Output stores are
// lane-linear; input reads are 64B/lane (4x float4).
__global__ void cvt_kernel(const float* __restrict__ Q, const float* __restrict__ Dm,
                           unsigned int* __restrict__ Q8, unsigned int* __restrict__ D8,
                           float* __restrict__ rowsum, unsigned int* __restrict__ cnt,
                           int qSlots, int B, int K) {
    const int gid = blockIdx.x * blockDim.x + threadIdx.x;
    if (gid < B) rowsum[gid] = 0.0f;
    if (gid == 0) cnt[0] = 0u;
    const float* src;
    unsigned int* dst;
    int s;
    if (gid < qSlots) { src = Q;  dst = Q8; s = gid; }
    else              { src = Dm; dst = D8; s = gid - qSlots; }
    const int l   = s & 63;
    const int c   = (s >> 6) & 15;
    const int k0b = (s >> 10) & 7;
    const int R   = s >> 13;
    const int row = R * 128 + (c >> 1) * 16 + (l & 15);
    const int k   = k0b * 128 + (c & 1) * 64 + (l >> 4) * 16;
    const float* p = src + (size_t)row * K + k;
    unsigned int w[4];
#pragma unroll
    for (int d = 0; d < 4; ++d) {
        float4 v = *(const float4*)(p + d * 4);
        int t = __builtin_amdgcn_cvt_pk_fp8_f32(v.x * PRESCALE, v.y * PRESCALE, 0, false);
        t = __builtin_amdgcn_cvt_pk_fp8_f32(v.z * PRESCALE, v.w * PRESCALE, t, true);
        w[d] = (unsigned int)t;
    }
    *(uint4*)(dst + (size_t)s * 4) = make_uint4(w[0], w[1], w[2], w[3]);
}

// ---------------- fused MX-fp8 GEMM + row sum-exp + pos + watcher final ----
// 1D grid of W+1 blocks (W = (B/128)*(N/128) workers + 1 watcher).
// Worker K-loop is byte-identical to R4's (single-buffer, 2 barriers).
__global__ __launch_bounds__(256, 2) void gemm_expsum_kernel(
        const unsigned int* __restrict__ Q8, const unsigned int* __restrict__ D8,
        const int* __restrict__ dper,
        float* __restrict__ rowsum, float* __restrict__ pos,
        unsigned int* __restrict__ cnt, float* __restrict__ out,
        int B, int K, int W) {
    __shared__ unsigned int Qs[4096];   // 16KB fragment-order image
    __shared__ unsigned int Ds[4096];
    __shared__ float redf[4];

    const int tid   = threadIdx.x;
    const int wave  = tid >> 6;
    const int lane  = tid & 63;

    // ---- watcher block: wait for all workers, then reduce ----
    if ((int)blockIdx.x == W) {
        if (tid == 0) {
            while (__hip_atomic_load(cnt, __ATOMIC_RELAXED,
                                     __HIP_MEMORY_SCOPE_AGENT) < (unsigned)W)
                __builtin_amdgcn_s_sleep(2);
        }
        __syncthreads();
        float s = 0.0f;
        for (int i = tid; i < B; i += 256) {
            float rs = __hip_atomic_load(&rowsum[i], __ATOMIC_RELAXED,
                                         __HIP_MEMORY_SCOPE_AGENT);
            float ps = __hip_atomic_load(&pos[i], __ATOMIC_RELAXED,
                                         __HIP_MEMORY_SCOPE_AGENT);
            s += __logf(rs) - ps;
        }
        s += __shfl_xor(s, 32);
        s += __shfl_xor(s, 16);
        s += __shfl_xor(s, 8);
        s += __shfl_xor(s, 4);
        s += __shfl_xor(s, 2);
        s += __shfl_xor(s, 1);
        if (lane == 0) redf[wave] = s;
        __syncthreads();
        if (tid == 0)
            out[0] = (redf[0] + redf[1] + redf[2] + redf[3]) / (float)B;
        return;
    }

    // ---- worker: XCD-aware decode. id&7 = XCD; each XCD owns an 8x32
    // (bx,by) rectangle so its L2 working set is 8 Q-tiles + 32 D-tiles.
    const int id  = blockIdx.x;
    const int xcd = id & 7;
    const int sl  = id >> 3;              // 0..255
    const int bx  = (xcd & 3) * 8 + (sl & 7);
    const int by  = (xcd >> 2) * 32 + (sl >> 3);

    const int lquad = lane >> 4;
    const int lm    = lane & 15;
    const int qbase = bx * 128;
    const int dbase = by * 128;
    const int KB    = K >> 7;             // 8 k-blocks

    // fragment-read dword offsets: chunk(rg, kh=lquad>>1)*256 + slot*4,
    // slot = ((lquad&1)*2 + t)*16 + lm
    const int slotofs = ((lquad & 1) * 32 + lm) * 4;   // t=0; t=1 adds 64
    const int aofs = ((wave >> 1) * 8 + (lquad >> 1)) * 256 + slotofs;
    const int bofs = ((wave & 1) * 8 + (lquad >> 1)) * 256 + slotofs;

    const unsigned int* Qg = Q8 + (size_t)bx * KB * 4096;
    const unsigned int* Dg = D8 + (size_t)by * KB * 4096;

    f32x4 acc[16];
#pragma unroll
    for (int t = 0; t < 16; ++t) acc[t] = (f32x4){0.f, 0.f, 0.f, 0.f};

    for (int kb = 0; kb < KB; ++kb) {
#pragma unroll
        for (int q = 0; q < 4; ++q) {
            const int c = wave * 4 + q;
            const unsigned int* g1 = Qg + kb * 4096 + c * 256 + lane * 4;
            __builtin_amdgcn_global_load_lds(
                (const __attribute__((address_space(1))) void*)g1,
                (__attribute__((address_space(3))) void*)(Qs + c * 256 + lane * 4),
                16, 0, 0);
            const unsigned int* g2 = Dg + kb * 4096 + c * 256 + lane * 4;
            __builtin_amdgcn_global_load_lds(
                (const __attribute__((address_space(1))) void*)g2,
                (__attribute__((address_space(3))) void*)(Ds + c * 256 + lane * 4),
                16, 0, 0);
        }
        __syncthreads();   // drains vmcnt -> LDS tiles ready

        i32x8 a8[4], b8[4];
#pragma unroll
        for (int i = 0; i < 4; ++i) {
            i32x4 lo = *(const i32x4*)(Qs + aofs + i * 512);
            i32x4 hi = *(const i32x4*)(Qs + aofs + i * 512 + 64);
            a8[i] = __builtin_shufflevector(lo, hi, 0, 1, 2, 3, 4, 5, 6, 7);
        }
#pragma unroll
        for (int j = 0; j < 4; ++j) {
            i32x4 lo = *(const i32x4*)(Ds + bofs + j * 512);
            i32x4 hi = *(const i32x4*)(Ds + bofs + j * 512 + 64);
            b8[j] = __builtin_shufflevector(lo, hi, 0, 1, 2, 3, 4, 5, 6, 7);
        }
#pragma unroll
        for (int i = 0; i < 4; ++i)
#pragma unroll
            for (int j = 0; j < 4; ++j)
                acc[i * 4 + j] = __builtin_amdgcn_mfma_scale_f32_16x16x128_f8f6f4(
                    a8[i], b8[j], acc[i * 4 + j], 0, 0, 0, SCALE_BYTE, 0, SCALE_BYTE);
        __syncthreads();   // all waves done reading before next stage
    }

    // epilogue. C layout: col = lane&15, row = (lane>>4)*4 + reg (16x16 shape)
    const int dp = dper[0];
#pragma unroll
    for (int i = 0; i < 4; ++i)
#pragma unroll
        for (int r = 0; r < 4; ++r) {
            const int gr   = qbase + (wave >> 1) * 64 + 16 * i + 4 * lquad + r;
            const int pcol = gr * dp - dbase;   // local col of positive, if here
            float e = 0.0f;
#pragma unroll
            for (int j = 0; j < 4; ++j) {
                float v = acc[i * 4 + j][r];
                if ((wave & 1) * 64 + 16 * j + lm == pcol)
                    __hip_atomic_store(&pos[gr], v * TEMP_INV, __ATOMIC_RELAXED,
                                       __HIP_MEMORY_SCOPE_AGENT);
                e += __expf(v * TEMP_INV);
            }
            e += __shfl_xor(e, 1);
            e += __shfl_xor(e, 2);
            e += __shfl_xor(e, 4);
            e += __shfl_xor(e, 8);
            if (lm == 0) atomicAdd(&rowsum[gr], e);
        }

    // Fence-free completion signal: __syncthreads makes every wave drain
    // vmcnt(0) first -> all this block's device-scope atomics/stores are
    // globally performed. Then ONE relaxed agent-scope add. No wbl2/inv.
    __syncthreads();
    if (tid == 0)
        __hip_atomic_fetch_add(cnt, 1u, __ATOMIC_RELAXED,
                               __HIP_MEMORY_SCOPE_AGENT);
}

extern "C" void kernel_launch(void* const* d_in, const int* in_sizes, int n_in,
                              void* d_out, int out_size, void* d_ws, size_t ws_size,
                              hipStream_t stream) {
    const float* Q   = (const float*)d_in[0];
    const float* Dm  = (const float*)d_in[1];
    const int* dper  = (const int*)d_in[2];
    float* out = (float*)d_out;

    const int DIM  = KD;
    const int B    = in_sizes[0] / DIM;   // 4096
    const int Ntot = in_sizes[1] / DIM;   // 8192

    unsigned int* Q8 = (unsigned int*)d_ws;
    unsigned int* D8 = Q8 + (size_t)B * DIM / 4;
    float* rowsum = (float*)(D8 + (size_t)Ntot * DIM / 4);
    float* pos = rowsum + B;
    unsigned int* cnt = (unsigned int*)(pos + B);

    const int qSlots = B * DIM / 16;            // 262144
    const int dSlots = Ntot * DIM / 16;         // 524288
    cvt_kernel<<<(qSlots + dSlots) / 256, 256, 0, stream>>>(
        Q, Dm, Q8, D8, rowsum, cnt, qSlots, B, DIM);

    const int W = (B / 128) * (Ntot / 128);     // 2048 workers
    gemm_expsum_kernel<<<W + 1, 256, 0, stream>>>(Q8, D8, dper, rowsum, pos,
                                                  cnt, out, B, DIM, W);
}

// Round 9
// 128.347 us; speedup vs baseline: 1.1358x; 1.1358x over previous
//
#include <hip/hip_runtime.h>

// InfoNCE loss:
//   loss = (1/B) * sum_i [ log(sum_j exp(Q_i . D_j / T)) - Q_i . D_{i*dp} / T ]
// Logits bounded (|logit| < ~10) -> no max-subtraction; per-row sum-exp is
// commutative -> atomicAdd merge across column-blocks.
//
// R9 = exact revert to R4, the verified best (total 127.0us, GEMM 44.7us =
// 1537 TF = 94% of the m148 MX-structure ladder rate; absmax 0.0).
// Structural escapes all measured and regressed:
//   R5 fused-final w/ per-block fences: GEMM 111us (L2 wbl2/inv storm)
//   R6 128x256/8-wave tile:             GEMM 68.4us (occupancy cliff)
//   R7 explicit LDS double-buffer:      GEMM 57.2us (occupancy cliff)
//   R8 watcher-fused final + XCD swizzle: GEMM 64us (FETCH halved but
//      dispatch gated on watcher tail -> locality wasn't the bottleneck)
// Aux time (total - GEMM) is 77-85us across SIX cvt designs and 2- vs
// 3-dispatch structures -> fixed harness cost + ~15us cvt traffic; not
// addressable from kernel code.
//
// Tiled layout (per matrix): for 128-row block R, 128-wide k-block k0b:
//   16KB image = 16 chunks x 1KB. Chunk c = rg*2 + kh (rg=0..7 16-row group,
//   kh=0..1 64-col half); slot l (16B) holds
//   X[R*128 + rg*16 + (l&15)][k0b*128 + kh*64 + (l>>4)*16 .. +16]   (fp8)
//
// ws layout (~12.1 MB):
//   [0)       Q8  B*K fp8     (4 MB)
//   [B*K)     D8  N*K fp8     (8 MB)
//   [+N*K)    rowsum B f32    (16 KB)  zeroed by cvt kernel
//   [+B*4)    pos    B f32    (16 KB)  written by gemm epilogue

#define TEMP_INV 50.0f
#define PRESCALE 16.0f
#define SCALE_BYTE 123   // e8m0: 2^(123-127) = 2^-4 per operand

typedef int   i32x4 __attribute__((ext_vector_type(4)));
typedef int   i32x8 __attribute__((ext_vector_type(8)));
typedef float f32x4 __attribute__((ext_vector_type(4)));

// ---------------- fp32 -> fp8 e4m3 (x16), pre-tiled; zero rowsum ----------
// One thread per 16B output slot. Output stores are perfectly lane-linear;
// input reads are 64B/lane contiguous (4x float4).
__global__ void cvt_kernel(const float* __restrict__ Q, const float* __restrict__ Dm,
                           unsigned int* __restrict__ Q8, unsigned int* __restrict__ D8,
                           float* __restrict__ rowsum, int qSlots, int B, int K) {
    const int gid = blockIdx.x * blockDim.x + threadIdx.x;
    if (gid < B) rowsum[gid] = 0.0f;
    const float* src;
    unsigned int* dst;
    int s;
    if (gid < qSlots) { src = Q;  dst = Q8; s = gid; }
    else              { src = Dm; dst = D8; s = gid - qSlots; }
    const int l   = s & 63;
    const int c   = (s >> 6) & 15;
    const int k0b = (s >> 10) & 7;
    const int R   = s >> 13;
    const int row = R * 128 + (c >> 1) * 16 + (l & 15);
    const int k   = k0b * 128 + (c & 1) * 64 + (l >> 4) * 16;
    const float* p = src + (size_t)row * K + k;
    unsigned int w[4];
#pragma unroll
    for (int d = 0; d < 4; ++d) {
        float4 v = *(const float4*)(p + d * 4);
        int t = __builtin_amdgcn_cvt_pk_fp8_f32(v.x * PRESCALE, v.y * PRESCALE, 0, false);
        t = __builtin_amdgcn_cvt_pk_fp8_f32(v.z * PRESCALE, v.w * PRESCALE, t, true);
        w[d] = (unsigned int)t;
    }
    *(uint4*)(dst + (size_t)s * 4) = make_uint4(w[0], w[1], w[2], w[3]);
}

// ---------------- fused MX-fp8 GEMM + row sum-exp + pos extraction --------
// grid (B/128, N/128), 256 threads (4 waves, 2x2 wave grid), BK=128.
__global__ __launch_bounds__(256, 2) void gemm_expsum_kernel(
        const unsigned int* __restrict__ Q8, const unsigned int* __restrict__ D8,
        const int* __restrict__ dper,
        float* __restrict__ rowsum, float* __restrict__ pos, int K) {
    __shared__ unsigned int Qs[4096];   // 16KB fragment-order image
    __shared__ unsigned int Ds[4096];

    const int tid   = threadIdx.x;
    const int wave  = tid >> 6;
    const int lane  = tid & 63;
    const int lquad = lane >> 4;
    const int lm    = lane & 15;
    const int qbase = blockIdx.x * 128;
    const int dbase = blockIdx.y * 128;
    const int KB    = K >> 7;           // 8 k-blocks

    // fragment-read dword offsets: chunk(rg, kh=lquad>>1)*256 + slot*4,
    // slot = ((lquad&1)*2 + t)*16 + lm
    const int slotofs = ((lquad & 1) * 32 + lm) * 4;   // t=0; t=1 adds 64
    const int aofs = ((wave >> 1) * 8 + (lquad >> 1)) * 256 + slotofs;
    const int bofs = ((wave & 1) * 8 + (lquad >> 1)) * 256 + slotofs;

    const unsigned int* Qg = Q8 + (size_t)blockIdx.x * KB * 4096;
    const unsigned int* Dg = D8 + (size_t)blockIdx.y * KB * 4096;

    f32x4 acc[16];
#pragma unroll
    for (int t = 0; t < 16; ++t) acc[t] = (f32x4){0.f, 0.f, 0.f, 0.f};

    for (int kb = 0; kb < KB; ++kb) {
#pragma unroll
        for (int q = 0; q < 4; ++q) {
            const int c = wave * 4 + q;
            const unsigned int* g1 = Qg + kb * 4096 + c * 256 + lane * 4;
            __builtin_amdgcn_global_load_lds(
                (const __attribute__((address_space(1))) void*)g1,
                (__attribute__((address_space(3))) void*)(Qs + c * 256 + lane * 4),
                16, 0, 0);
            const unsigned int* g2 = Dg + kb * 4096 + c * 256 + lane * 4;
            __builtin_amdgcn_global_load_lds(
                (const __attribute__((address_space(1))) void*)g2,
                (__attribute__((address_space(3))) void*)(Ds + c * 256 + lane * 4),
                16, 0, 0);
        }
        __syncthreads();   // drains vmcnt -> LDS tiles ready

        i32x8 a8[4], b8[4];
#pragma unroll
        for (int i = 0; i < 4; ++i) {
            i32x4 lo = *(const i32x4*)(Qs + aofs + i * 512);
            i32x4 hi = *(const i32x4*)(Qs + aofs + i * 512 + 64);
            a8[i] = __builtin_shufflevector(lo, hi, 0, 1, 2, 3, 4, 5, 6, 7);
        }
#pragma unroll
        for (int j = 0; j < 4; ++j) {
            i32x4 lo = *(const i32x4*)(Ds + bofs + j * 512);
            i32x4 hi = *(const i32x4*)(Ds + bofs + j * 512 + 64);
            b8[j] = __builtin_shufflevector(lo, hi, 0, 1, 2, 3, 4, 5, 6, 7);
        }
#pragma unroll
        for (int i = 0; i < 4; ++i)
#pragma unroll
            for (int j = 0; j < 4; ++j)
                acc[i * 4 + j] = __builtin_amdgcn_mfma_scale_f32_16x16x128_f8f6f4(
                    a8[i], b8[j], acc[i * 4 + j], 0, 0, 0, SCALE_BYTE, 0, SCALE_BYTE);
        __syncthreads();   // all waves done reading before next stage
    }

    // epilogue. C layout: col = lane&15, row = (lane>>4)*4 + reg (16x16 shape)
    const int dp = dper[0];
#pragma unroll
    for (int i = 0; i < 4; ++i)
#pragma unroll
        for (int r = 0; r < 4; ++r) {
            const int gr   = qbase + (wave >> 1) * 64 + 16 * i + 4 * lquad + r;
            const int pcol = gr * dp - dbase;   // local col of positive, if here
            float e = 0.0f;
#pragma unroll
            for (int j = 0; j < 4; ++j) {
                float v = acc[i * 4 + j][r];
                if ((wave & 1) * 64 + 16 * j + lm == pcol) pos[gr] = v * TEMP_INV;
                e += __expf(v * TEMP_INV);
            }
            e += __shfl_xor(e, 1);
            e += __shfl_xor(e, 2);
            e += __shfl_xor(e, 4);
            e += __shfl_xor(e, 8);
            if (lm == 0) atomicAdd(&rowsum[gr], e);
        }
}

// ---------------- final: loss = sum(log(rowsum) - pos)/B ----------------
__global__ void final_kernel(const float* __restrict__ rowsum,
                             const float* __restrict__ pos,
                             float* __restrict__ out, int B) {
    __shared__ float red[16];
    int tid = threadIdx.x;   // 1024 threads
    float s = 0.0f;
    for (int i = tid; i < B; i += blockDim.x)
        s += __logf(rowsum[i]) - pos[i];
    s += __shfl_xor(s, 32);
    s += __shfl_xor(s, 16);
    s += __shfl_xor(s, 8);
    s += __shfl_xor(s, 4);
    s += __shfl_xor(s, 2);
    s += __shfl_xor(s, 1);
    int w = tid >> 6, l = tid & 63;
    if (l == 0) red[w] = s;
    __syncthreads();
    if (tid == 0) {
        float t = 0.0f;
        int nw = blockDim.x >> 6;
        for (int i = 0; i < nw; ++i) t += red[i];
        out[0] = t / (float)B;
    }
}

extern "C" void kernel_launch(void* const* d_in, const int* in_sizes, int n_in,
                              void* d_out, int out_size, void* d_ws, size_t ws_size,
                              hipStream_t stream) {
    const float* Q   = (const float*)d_in[0];
    const float* Dm  = (const float*)d_in[1];
    const int* dper  = (const int*)d_in[2];
    float* out = (float*)d_out;

    const int DIM  = 1024;
    const int B    = in_sizes[0] / DIM;   // 4096
    const int Ntot = in_sizes[1] / DIM;   // 8192

    unsigned int* Q8 = (unsigned int*)d_ws;
    unsigned int* D8 = Q8 + (size_t)B * DIM / 4;
    float* rowsum = (float*)(D8 + (size_t)Ntot * DIM / 4);
    float* pos = rowsum + B;

    const int qSlots = B * DIM / 16;            // 262144
    const int dSlots = Ntot * DIM / 16;         // 524288
    cvt_kernel<<<(qSlots + dSlots) / 256, 256, 0, stream>>>(
        Q, Dm, Q8, D8, rowsum, qSlots, B, DIM);

    dim3 grid(B / 128, Ntot / 128);
    gemm_expsum_kernel<<<grid, 256, 0, stream>>>(Q8, D8, dper, rowsum, pos, DIM);

    final_kernel<<<1, 1024, 0, stream>>>(rowsum, pos, out, B);
}